// Round 1
// baseline (585.958 us; speedup 1.0000x reference)
//
#include <hip/hip_runtime.h>

typedef __attribute__((ext_vector_type(4))) float floatx4;
typedef __attribute__((ext_vector_type(8))) short bf16x8;

__device__ __forceinline__ unsigned short f2bf(float f) {
    union { float f; unsigned u; } v; v.f = f;
    unsigned r = v.u + 0x7fffu + ((v.u >> 16) & 1u);  // RNE
    return (unsigned short)(r >> 16);
}

// ---------------------------------------------------------------------------
// prep: pack weights into MFMA B-operand fragment blobs (bf16) + fuse biases.
// Wcat blob [kc=0..47][ntg=0..31][lane=0..63][j=0..7]:
//   element B[k][n], k = kc*32 + (lane>>4)*8 + j, n = ntg*16 + (lane&15)
//   k < 1024 -> W1[c][k][s] (c=n>>5, s=n&31), else W2[c][k-1024][s]
// W3 blob   [kc=0..15][ntg=0..31][lane][j]: B[k][n] = W3flat[k*512 + n]
// bias12[n] = b1flat[n] + b2flat[n];  bias3s[n] = sum_c b3[c*512+n]
// ---------------------------------------------------------------------------
__global__ void prep_kernel(const float* __restrict__ W1, const float* __restrict__ b1,
                            const float* __restrict__ W2, const float* __restrict__ b2,
                            const float* __restrict__ W3, const float* __restrict__ b3,
                            unsigned short* __restrict__ wcat, unsigned short* __restrict__ w3f,
                            float* __restrict__ bias12, float* __restrict__ bias3s)
{
    int tid = blockIdx.x * 256 + threadIdx.x;
    if (tid < 98304) {                       // 48 * 32 * 64 fragment-lanes
        int l  = tid & 63;
        int nt = (tid >> 6) & 31;
        int kc = tid >> 11;                  // 0..47
        int n  = nt * 16 + (l & 15);
        int k0 = kc * 32 + ((l >> 4) << 3);
        int c = n >> 5, s = n & 31;
        union { unsigned short us[8]; int4 v; } pk;
        const float* src = (k0 < 1024) ? (W1 + c * 32768 + k0 * 32 + s)
                                       : (W2 + c * 16384 + (k0 - 1024) * 32 + s);
        #pragma unroll
        for (int j = 0; j < 8; ++j) pk.us[j] = f2bf(src[j * 32]);
        *(int4*)(wcat + (size_t)tid * 8) = pk.v;
    } else if (tid < 131072) {               // 16 * 32 * 64 fragment-lanes for W3
        int t  = tid - 98304;
        int l  = t & 63;
        int nt = (t >> 6) & 31;
        int kc = t >> 11;                    // 0..15
        int n  = nt * 16 + (l & 15);
        int k0 = kc * 32 + ((l >> 4) << 3);
        union { unsigned short us[8]; int4 v; } pk;
        const float* src = W3 + k0 * 512 + n;
        #pragma unroll
        for (int j = 0; j < 8; ++j) pk.us[j] = f2bf(src[j * 512]);
        *(int4*)(w3f + (size_t)t * 8) = pk.v;
    } else if (tid < 131584) {
        int n = tid - 131072;
        bias12[n] = b1[n] + b2[n];
        float sacc = 0.f;
        #pragma unroll
        for (int c = 0; c < 16; ++c) sacc += b3[c * 512 + n];
        bias3s[n] = sacc;
    }
}

// ---------------------------------------------------------------------------
// fused main: per block 64 rows. 256 threads = 4 waves, wave w owns cols
// [w*128, w*128+128). Phase 1: H_pre = [app|sp] @ Wcat (K=1536), A staged
// fp32->bf16 into double-buffered LDS frag blobs, B frags direct from L2.
// Phase 2: relu(H_pre + bias12) -> bf16 Hf (A-fragment layout).
// Phase 3: out = relu(Hf @ W3 + bias3s), W3 frags direct from L2.
// MFMA 16x16x32 bf16; A-frag: lane l holds A[m=l&15][k=(l>>4)*8+j];
// B-frag: B[k=(l>>4)*8+j][n=l&15]; C/D: col=l&15, row=(l>>4)*4+reg.
// ---------------------------------------------------------------------------
__global__ __launch_bounds__(256, 2) void fused_main(
    const float* __restrict__ app, const float* __restrict__ sp,
    const unsigned short* __restrict__ wcat, const unsigned short* __restrict__ w3f,
    const float* __restrict__ bias12, const float* __restrict__ bias3s,
    float* __restrict__ out)
{
    __shared__ unsigned short As[2][4][64][8];   // 8 KB  A-frag staging (dbuf)
    __shared__ unsigned short Hf[4][16][64][8];  // 64 KB H in A-frag layout

    const int tid = (int)threadIdx.x;
    const int w   = tid >> 6;
    const int l   = tid & 63;
    const int rowbase = (int)blockIdx.x * 64;

    // cooperative A-staging mapping: thread -> (row, 8-wide k-chunk)
    const int sr  = tid >> 2;                 // 0..63
    const int scc = tid & 3;                  // 0..3  (k-chunk of 8)
    const float* appsrc = app + (size_t)(rowbase + sr) * 1024 + scc * 8;
    const float* spsrc  = sp  + (size_t)(rowbase + sr) * 512  + scc * 8;
    unsigned short* as0 = &As[0][sr >> 4][scc * 16 + (sr & 15)][0];
    unsigned short* as1 = &As[1][sr >> 4][scc * 16 + (sr & 15)][0];

    floatx4 acc[4][8];
    #pragma unroll
    for (int mt = 0; mt < 4; ++mt)
        #pragma unroll
        for (int nt = 0; nt < 8; ++nt)
            acc[mt][nt] = (floatx4){0.f, 0.f, 0.f, 0.f};

    // prologue: stage kb = 0
    {
        float4 p0 = *(const float4*)(appsrc);
        float4 p1 = *(const float4*)(appsrc + 4);
        union { unsigned short us[8]; int4 v; } pk;
        pk.us[0] = f2bf(p0.x); pk.us[1] = f2bf(p0.y); pk.us[2] = f2bf(p0.z); pk.us[3] = f2bf(p0.w);
        pk.us[4] = f2bf(p1.x); pk.us[5] = f2bf(p1.y); pk.us[6] = f2bf(p1.z); pk.us[7] = f2bf(p1.w);
        *(int4*)as0 = pk.v;
    }

    // ---- phase 1 ----
    for (int kb = 0; kb < 48; ++kb) {
        __syncthreads();
        const int buf = kb & 1;
        float4 p0, p1;
        if (kb + 1 < 48) {                    // prefetch next A chunk (HBM)
            const float* src = (kb + 1 < 32) ? (appsrc + (kb + 1) * 32)
                                             : (spsrc + (kb + 1 - 32) * 32);
            p0 = *(const float4*)(src);
            p1 = *(const float4*)(src + 4);
        }
        bf16x8 bfrag[8];
        #pragma unroll
        for (int nt = 0; nt < 8; ++nt)
            bfrag[nt] = *(const bf16x8*)(wcat + (((size_t)kb * 32 + w * 8 + nt) * 64 + l) * 8);
        bf16x8 afrag[4];
        #pragma unroll
        for (int mt = 0; mt < 4; ++mt)
            afrag[mt] = *(const bf16x8*)(&As[buf][mt][l][0]);
        #pragma unroll
        for (int mt = 0; mt < 4; ++mt)
            #pragma unroll
            for (int nt = 0; nt < 8; ++nt)
                acc[mt][nt] = __builtin_amdgcn_mfma_f32_16x16x32_bf16(
                    afrag[mt], bfrag[nt], acc[mt][nt], 0, 0, 0);
        if (kb + 1 < 48) {                    // stage prefetched chunk into other buffer
            union { unsigned short us[8]; int4 v; } pk;
            pk.us[0] = f2bf(p0.x); pk.us[1] = f2bf(p0.y); pk.us[2] = f2bf(p0.z); pk.us[3] = f2bf(p0.w);
            pk.us[4] = f2bf(p1.x); pk.us[5] = f2bf(p1.y); pk.us[6] = f2bf(p1.z); pk.us[7] = f2bf(p1.w);
            *(int4*)((buf == 0) ? as1 : as0) = pk.v;
        }
    }

    // ---- phase 2: relu + bias, write Hf in A-frag layout ----
    #pragma unroll
    for (int nt = 0; nt < 8; ++nt) {
        const int colg = w * 128 + nt * 16 + (l & 15);
        const float bv = bias12[colg];
        const int kc  = colg >> 5;
        const int lhi = ((colg >> 3) & 3) << 4;
        const int j   = colg & 7;
        #pragma unroll
        for (int mt = 0; mt < 4; ++mt)
            #pragma unroll
            for (int r = 0; r < 4; ++r) {
                const int rlow = ((l >> 4) << 2) + r;      // rowg & 15
                float v = acc[mt][nt][r] + bv;
                v = fmaxf(v, 0.f);
                Hf[mt][kc][lhi + rlow][j] = f2bf(v);
            }
    }
    __syncthreads();

    // ---- phase 3 ----
    #pragma unroll
    for (int mt = 0; mt < 4; ++mt)
        #pragma unroll
        for (int nt = 0; nt < 8; ++nt)
            acc[mt][nt] = (floatx4){0.f, 0.f, 0.f, 0.f};

    for (int kc = 0; kc < 16; ++kc) {
        bf16x8 bfrag[8];
        #pragma unroll
        for (int nt = 0; nt < 8; ++nt)
            bfrag[nt] = *(const bf16x8*)(w3f + (((size_t)kc * 32 + w * 8 + nt) * 64 + l) * 8);
        bf16x8 afrag[4];
        #pragma unroll
        for (int mt = 0; mt < 4; ++mt)
            afrag[mt] = *(const bf16x8*)(&Hf[mt][kc][l][0]);
        #pragma unroll
        for (int mt = 0; mt < 4; ++mt)
            #pragma unroll
            for (int nt = 0; nt < 8; ++nt)
                acc[mt][nt] = __builtin_amdgcn_mfma_f32_16x16x32_bf16(
                    afrag[mt], bfrag[nt], acc[mt][nt], 0, 0, 0);
    }

    // ---- epilogue ----
    #pragma unroll
    for (int nt = 0; nt < 8; ++nt) {
        const int colg = w * 128 + nt * 16 + (l & 15);
        const float bv = bias3s[colg];
        #pragma unroll
        for (int mt = 0; mt < 4; ++mt)
            #pragma unroll
            for (int r = 0; r < 4; ++r) {
                const int rowg = mt * 16 + ((l >> 4) << 2) + r;
                float v = acc[mt][nt][r] + bv;
                v = fmaxf(v, 0.f);
                out[(size_t)(rowbase + rowg) * 512 + colg] = v;
            }
    }
}

extern "C" void kernel_launch(void* const* d_in, const int* in_sizes, int n_in,
                              void* d_out, int out_size, void* d_ws, size_t ws_size,
                              hipStream_t stream)
{
    const float* app = (const float*)d_in[0];
    const float* sp  = (const float*)d_in[1];
    const float* W1  = (const float*)d_in[2];
    const float* b1  = (const float*)d_in[3];
    const float* W2  = (const float*)d_in[4];
    const float* b2  = (const float*)d_in[5];
    const float* W3  = (const float*)d_in[6];
    const float* b3  = (const float*)d_in[7];

    char* ws = (char*)d_ws;
    unsigned short* wcat  = (unsigned short*)(ws);             // 1,572,864 B
    unsigned short* w3f   = (unsigned short*)(ws + 1572864);   //   524,288 B
    float*          b12   = (float*)(ws + 2097152);            //     2,048 B
    float*          b3s   = (float*)(ws + 2099200);            //     2,048 B

    prep_kernel<<<514, 256, 0, stream>>>(W1, b1, W2, b2, W3, b3, wcat, w3f, b12, b3s);

    float* outp = (float*)d_out;
    fused_main<<<65536 / 64, 256, 0, stream>>>(app, sp, wcat, w3f, b12, b3s, outp);
}